// Round 5
// baseline (60.315 us; speedup 1.0000x reference)
//
#include <hip/hip_runtime.h>

#define H_OBJ 64
#define W_OBJ 64
#define HIN 256
#define WIN 256
#define NCH 3
#define G 4                       // output rows per iteration
#define NSLOT (2*G)               // staged input rows per iteration
#define ROWS_PER_BLOCK 32         // 2 blocks per batch
#define NITER (ROWS_PER_BLOCK/G)  // 8

// One block = 256 threads handles 32 output rows of one batch.
// Per iteration: stage 8 input rows x 3ch (24KB) coalesced, sample from LDS.
__global__ __launch_bounds__(256) void stn_glimpse_kernel(
    const float* __restrict__ image,   // [N,3,256,256]
    const float* __restrict__ zwhere,  // [N,4]  (y,x,h,w)
    const int* __restrict__ inv_p,     // [1]
    float* __restrict__ out)           // [N, 3*64*64]
{
    __shared__ float buf[NSLOT][NCH][WIN];   // 24 KB
    float* const bufF = &buf[0][0][0];

    const int b    = blockIdx.x;
    const int n    = b >> 1;
    const int half = b & 1;
    const int t    = threadIdx.x;
    const int j    = t & 63;     // output column
    const int ii   = t >> 6;     // row within group (0..3)

    const float zy = zwhere[n*4+0];
    const float zx = zwhere[n*4+1];
    const float zh = zwhere[n*4+2];
    const float zw = zwhere[n*4+3];
    const float y  = zy*2.0f - 1.0f;
    const float x  = zx*2.0f - 1.0f;
    const float rw = 1.0f/zw;
    const float rh = 1.0f/zh;
    const int inv  = *inv_p;     // uniform branch

    const float* imgN = image + (size_t)n * (NCH*HIN*WIN);
    float* outN = out + (size_t)n * (NCH*H_OBJ*W_OBJ);

    // ---- x-tap: depends only on j, compute once ----
    const float gx = -1.0f + (2.0f/63.0f)*(float)j;
    float grid_x = inv ? (gx - x)*rw : (zw*gx + x);
    float ixf = (grid_x + 1.0f)*0.5f*(float)(WIN-1);
    ixf = fminf(fmaxf(ixf, 0.0f), (float)(WIN-1));
    const float ix0f = floorf(ixf);
    const float wx   = ixf - ix0f;
    const int ix0    = (int)ix0f;
    const int xbase  = min(ix0, WIN-2);
    const bool lo    = (ix0 < WIN-1);

    // uniform: input row index for a given output row i, tap parity par
    auto inrow = [&](int i, int par) -> int {
        const float gy = -1.0f + (2.0f/63.0f)*(float)i;
        float gyy = inv ? (gy - y)*rh : (zh*gy + y);
        float iyf = (gyy + 1.0f)*0.5f*(float)(HIN-1);
        iyf = fminf(fmaxf(iyf, 0.0f), (float)(HIN-1));
        const int iy0 = (int)floorf(iyf);
        return par ? min(iy0+1, HIN-1) : iy0;
    };

    // issue the 6 coalesced float4 loads for iteration k into regs
    auto issue_loads = [&](int k, float4* regs) {
        const int i0 = half*ROWS_PER_BLOCK + k*G;
#pragma unroll
        for (int q = 0; q < 6; ++q) {
            const int p    = q*4 + ii;        // panel 0..23 (wave-uniform)
            const int slot = p/3;
            const int ch   = p - slot*3;
            const int row  = inrow(i0 + (slot>>1), slot&1);
            const float* src = imgN + ch*(HIN*WIN) + row*WIN + 4*j;
            __builtin_memcpy(&regs[q], src, sizeof(float4));
        }
    };

    float4 regs[6];
    issue_loads(0, regs);

    for (int k = 0; k < NITER; ++k) {
        __syncthreads();   // previous compute done -> LDS writable
#pragma unroll
        for (int q = 0; q < 6; ++q)
            reinterpret_cast<float4*>(bufF)[q*256 + t] = regs[q];
        if (k+1 < NITER) issue_loads(k+1, regs);   // overlap with compute
        __syncthreads();   // LDS staged

        // ---- compute: this thread's pixel (row i0+ii, col j), 3 channels ----
        const int i = half*ROWS_PER_BLOCK + k*G + ii;
        const float gy = -1.0f + (2.0f/63.0f)*(float)i;
        float gyy = inv ? (gy - y)*rh : (zh*gy + y);
        float iyf = (gyy + 1.0f)*0.5f*(float)(HIN-1);
        iyf = fminf(fmaxf(iyf, 0.0f), (float)(HIN-1));
        const float wy = iyf - floorf(iyf);

        const float w00 = (1.0f - wx)*(1.0f - wy);
        const float w01 = wx*(1.0f - wy);
        const float w10 = (1.0f - wx)*wy;
        const float w11 = wx*wy;

        const int sT = 2*ii, sB = 2*ii + 1;
#pragma unroll
        for (int c = 0; c < NCH; ++c) {
            float2 top, bot;
            __builtin_memcpy(&top, &buf[sT][c][xbase], sizeof(float2));
            __builtin_memcpy(&bot, &buf[sB][c][xbase], sizeof(float2));
            const float v00 = lo ? top.x : top.y;
            const float v01 = top.y;
            const float v10 = lo ? bot.x : bot.y;
            const float v11 = bot.y;
            __builtin_nontemporal_store(
                v00*w00 + v01*w01 + v10*w10 + v11*w11,
                &outN[c*(H_OBJ*W_OBJ) + i*W_OBJ + j]);
        }
    }
}

extern "C" void kernel_launch(void* const* d_in, const int* in_sizes, int n_in,
                              void* d_out, int out_size, void* d_ws, size_t ws_size,
                              hipStream_t stream) {
    const float* image  = (const float*)d_in[0];
    const float* zwhere = (const float*)d_in[1];
    const int*   inv    = (const int*)d_in[2];
    float*       out    = (float*)d_out;

    const int nBatch = in_sizes[1] / 4;   // 512
    stn_glimpse_kernel<<<nBatch * 2, 256, 0, stream>>>(image, zwhere, inv, out);
}